// Round 2
// baseline (535.311 us; speedup 1.0000x reference)
//
#include <hip/hip_runtime.h>
#include <hip/hip_bf16.h>

// VoxelEncoding: trilinear interpolation of 8 corner embeddings per point.
// All float tensors are fp32 (per reference); indices int32; output fp32 (N,16).

__global__ __launch_bounds__(256) void VoxelEncoding_kernel(
    const float* __restrict__ pts,   // (N,3) f32
    const int*   __restrict__ p2v,   // (N,)  i32
    const float* __restrict__ emb,   // (N_EMB,16) f32
    const float* __restrict__ cp,    // (N_VOX,3) f32
    const int*   __restrict__ c2c,   // (N_VOX,8) i32
    const float* __restrict__ vox,   // (1,) f32
    float*       __restrict__ out,   // (N,16) f32
    int N)
{
    int n = blockIdx.x * blockDim.x + threadIdx.x;
    if (n >= N) return;

    const int v = p2v[n];
    const float inv_vs = 1.0f / vox[0];

    const float* pp  = pts + 3 * (size_t)n;
    const float* cpp = cp  + 3 * (size_t)v;
    const float px = (pp[0] - cpp[0]) * inv_vs + 0.5f;
    const float py = (pp[1] - cpp[1]) * inv_vs + 0.5f;
    const float pz = (pp[2] - cpp[2]) * inv_vs + 0.5f;

    // 8 corner embedding indices (32 B = two dwordx4)
    const int4* c4 = (const int4*)(c2c + 8 * (size_t)v);
    const int4 ci0 = c4[0];
    const int4 ci1 = c4[1];
    const int cidx[8] = {ci0.x, ci0.y, ci0.z, ci0.w, ci1.x, ci1.y, ci1.z, ci1.w};

    // trilinear weights; corner c = (i<<2)|(j<<1)|k (meshgrid 'ij' order);
    // offset=1 -> p, offset=0 -> 1-p
    const float wx[2] = {1.0f - px, px};
    const float wy[2] = {1.0f - py, py};
    const float wz[2] = {1.0f - pz, pz};

    float4 a0 = make_float4(0.f, 0.f, 0.f, 0.f);
    float4 a1 = a0, a2 = a0, a3 = a0;

    #pragma unroll
    for (int c = 0; c < 8; ++c) {
        const float w = wx[(c >> 2) & 1] * wy[(c >> 1) & 1] * wz[c & 1];
        const float4* er = (const float4*)(emb + 16 * (size_t)cidx[c]);
        const float4 e0 = er[0];
        const float4 e1 = er[1];
        const float4 e2 = er[2];
        const float4 e3 = er[3];
        a0.x = fmaf(w, e0.x, a0.x); a0.y = fmaf(w, e0.y, a0.y);
        a0.z = fmaf(w, e0.z, a0.z); a0.w = fmaf(w, e0.w, a0.w);
        a1.x = fmaf(w, e1.x, a1.x); a1.y = fmaf(w, e1.y, a1.y);
        a1.z = fmaf(w, e1.z, a1.z); a1.w = fmaf(w, e1.w, a1.w);
        a2.x = fmaf(w, e2.x, a2.x); a2.y = fmaf(w, e2.y, a2.y);
        a2.z = fmaf(w, e2.z, a2.z); a2.w = fmaf(w, e2.w, a2.w);
        a3.x = fmaf(w, e3.x, a3.x); a3.y = fmaf(w, e3.y, a3.y);
        a3.z = fmaf(w, e3.z, a3.z); a3.w = fmaf(w, e3.w, a3.w);
    }

    float4* op = (float4*)(out + 16 * (size_t)n);
    op[0] = a0; op[1] = a1; op[2] = a2; op[3] = a3;
}

extern "C" void kernel_launch(void* const* d_in, const int* in_sizes, int n_in,
                              void* d_out, int out_size, void* d_ws, size_t ws_size,
                              hipStream_t stream) {
    const float* pts = (const float*)d_in[0];
    const int*   p2v = (const int*)d_in[1];
    const float* emb = (const float*)d_in[2];
    const float* cp  = (const float*)d_in[3];
    const int*   c2c = (const int*)d_in[4];
    const float* vox = (const float*)d_in[5];
    float*       out = (float*)d_out;

    const int N = in_sizes[1];  // N_PTS = 2,000,000
    const int block = 256;
    const int grid = (N + block - 1) / block;
    VoxelEncoding_kernel<<<grid, block, 0, stream>>>(pts, p2v, emb, cp, c2c, vox, out, N);
}